// Round 8
// baseline (1146.383 us; speedup 1.0000x reference)
//
#include <hip/hip_runtime.h>
#include <hip/hip_bf16.h>

#define B_ 2048
#define S_ 71
#define D_ 768
#define H_ 4
#define DH_ 192
#define TD_ 2304            // 3*D
#define M_ (B_ * S_)        // 145408 = 1136*128
#define TEXT_ 35
#define NKT2 24             // 768 / 32 K-tiles

typedef unsigned short u16;
typedef unsigned int u32;
typedef __attribute__((ext_vector_type(4))) float f32x4;
typedef __attribute__((ext_vector_type(8))) short bf16x8;

__device__ __forceinline__ u16 f2bf(float f) {
  u32 u = __float_as_uint(f);
  u32 r = (u + 0x7FFFu + ((u >> 16) & 1u)) >> 16;  // RNE
  return (u16)r;
}
__device__ __forceinline__ float bf2f(u16 x) {
  return __uint_as_float(((u32)x) << 16);
}

typedef __attribute__((address_space(1))) const unsigned int GASU;
typedef __attribute__((address_space(3))) unsigned int LASU;
__device__ __forceinline__ void gload16(const void* g, void* l) {
  __builtin_amdgcn_global_load_lds((GASU*)g, (LASU*)l, 16, 0, 0);
}

#define PHASE_BAR() do { __builtin_amdgcn_s_barrier(); asm volatile("" ::: "memory"); } while (0)

// ---------------------------------------------------------------------------
// fp32 -> bf16 elementwise, 8 elems/thread, exact grid
__global__ __launch_bounds__(256) void k_cvt_bf16(const float* __restrict__ in,
                                                  u16* __restrict__ out, int n8) {
  int idx = blockIdx.x * 256 + threadIdx.x;
  if (idx >= n8) return;
  const float4* p = (const float4*)(in + (size_t)idx * 8);
  float4 a = p[0], b = p[1];
  uint4 o;
  o.x = (u32)f2bf(a.x) | ((u32)f2bf(a.y) << 16);
  o.y = (u32)f2bf(a.z) | ((u32)f2bf(a.w) << 16);
  o.z = (u32)f2bf(b.x) | ((u32)f2bf(b.y) << 16);
  o.w = (u32)f2bf(b.z) | ((u32)f2bf(b.w) << 16);
  *(uint4*)(out + (size_t)idx * 8) = o;
}

// ---------------------------------------------------------------------------
// w_out [e][d] -> w_outT [d][e]  (768x768 fp32, tiny)
__global__ void k_transpose768(const float* __restrict__ in, float* __restrict__ out) {
  int idx = blockIdx.x * 256 + threadIdx.x;
  int e = idx / 768, d = idx % 768;
  out[(size_t)d * 768 + e] = in[idx];
}

// ---------------------------------------------------------------------------
// GEMM: C[M,2304] = A[M,768](bf16) * Bw[2304,768](bf16 n-major), bias + phi
// epilogue. OCCUPANCY-FIRST build: 128x256 tile, BK=32, dbuf LDS = 48 KiB,
// 8 waves of 64x64 (acc=64 regs), __launch_bounds__(512,4) caps 128 VGPR ->
// 2 blocks/CU resident (prior 256^2/128KiB/240reg builds were 1 block/CU and
// all schedule variants pinned at ~34% MfmaUtil: every barrier/drain/
// transition was exposed). Simple 2-phase loop; cross-block TLP hides stalls.
// BK=32 rows are 64B -> b128 frag reads are bank-balanced, no swizzle needed.
__global__ __launch_bounds__(512, 4) void k_gemm_qkv(
    const u16* __restrict__ Abf,  // [M_,768] bf16
    const u16* __restrict__ Bw,   // [2304,768] bf16 (n-major)
    const float* __restrict__ bias, // [2304]
    u16* __restrict__ C)            // [M_,2304] bf16, phi on cols<1536
{
  // per buffer (u16): A [128][32] at 0, B [256][32] at 4096; buf stride 12288
  __shared__ u16 sm[24576];   // 48 KiB
  int t = threadIdx.x;
  int lane = t & 63, wid = t >> 6;
  int wr = wid >> 2, wc = wid & 3;     // 2 x 4 wave grid, wave tile 64x64
  int lr = lane & 15;
  int g4 = lane >> 4;                  // K granule (8 u16 each)

  // XCD-bijective swizzle: nwg = 10224 = 8 * 1278; bn inner -> A-panel reuse
  int swz = (blockIdx.x & 7) * 1278 + (blockIdx.x >> 3);
  int bm = swz / 9, bn = swz % 9;
  const size_t arow0 = (size_t)bm * 128;
  const int bcol0 = bn * 256;

  // staging: 1536 16B-chunks per K-tile; 3 insts/thread (A:1, B:2)
  const u16* gsrc[3];
  int ldst[3];
  {
    int ci = t;                         // A: row = ci>>2, kchunk = ci&3
    gsrc[0] = Abf + (arow0 + (ci >> 2)) * 768 + (ci & 3) * 8;
    ldst[0] = ci * 8;
  }
#pragma unroll
  for (int j = 1; j < 3; ++j) {
    int ci = (j - 1) * 512 + t;         // B: row = ci>>2 (0..255)
    gsrc[j] = Bw + (size_t)(bcol0 + (ci >> 2)) * 768 + (ci & 3) * 8;
    ldst[j] = 4096 + ci * 8;
  }

#define STAGE(buf, ktu) do { \
  gload16(gsrc[0] + (ktu), &sm[(buf) + ldst[0]]); \
  gload16(gsrc[1] + (ktu), &sm[(buf) + ldst[1]]); \
  gload16(gsrc[2] + (ktu), &sm[(buf) + ldst[2]]); \
} while (0)

  // fragment read offsets (u16 units)
  int aoff = (wr * 64 + lr) * 32 + g4 * 8;           // + mi*512
  int boff = 4096 + (wc * 64 + lr) * 32 + g4 * 8;    // + ni*512

  f32x4 acc[4][4] = {};

  // prologue: stage tile 0
  STAGE(0, 0);
  asm volatile("s_waitcnt vmcnt(0)" ::: "memory");
  PHASE_BAR();

  for (int T = 0; T < NKT2; ++T) {
    int cur = (T & 1) * 12288;
    int nxt = 12288 - cur;
    if (T < NKT2 - 1) STAGE(nxt, (T + 1) * 32);
    bf16x8 a[4], b[4];
#pragma unroll
    for (int mi = 0; mi < 4; ++mi) a[mi] = *(const bf16x8*)(&sm[cur + aoff + mi * 512]);
#pragma unroll
    for (int ni = 0; ni < 4; ++ni) b[ni] = *(const bf16x8*)(&sm[cur + boff + ni * 512]);
    __builtin_amdgcn_s_setprio(1);
#pragma unroll
    for (int mi = 0; mi < 4; ++mi)
#pragma unroll
      for (int ni = 0; ni < 4; ++ni)
        acc[mi][ni] = __builtin_amdgcn_mfma_f32_16x16x32_bf16(a[mi], b[ni], acc[mi][ni], 0, 0, 0);
    __builtin_amdgcn_s_setprio(0);
    asm volatile("s_waitcnt vmcnt(0)" ::: "memory");   // next tile landed
    PHASE_BAR();                                       // WAR: cur free after this
  }

  // epilogue: bias + phi, bf16 stores
#pragma unroll
  for (int mi = 0; mi < 4; ++mi) {
#pragma unroll
    for (int ni = 0; ni < 4; ++ni) {
      int col = bcol0 + wc * 64 + ni * 16 + lr;
      float bb = bias[col];
#pragma unroll
      for (int i = 0; i < 4; ++i) {
        size_t row = arow0 + wr * 64 + mi * 16 + g4 * 4 + i;
        float v = acc[mi][ni][i] + bb;
        if (col < 1536) v = (v > 0.0f) ? (v + 1.0f) : __expf(v);
        C[row * TD_ + col] = f2bf(v);
      }
    }
  }
#undef STAGE
}

// ---------------------------------------------------------------------------
// Attention core, one block per (b,h). Never materializes kv[192][192].
#define ALD 196  // LDS stride for 192-wide bf16 rows

__global__ __launch_bounds__(256) void k_attn(
    const u16* __restrict__ qkv,  // [M_,2304] bf16
    float* __restrict__ mt, float* __restrict__ mi)  // [B_,768] fp32
{
  __shared__ u16 qs[S_ * ALD];
  __shared__ u16 ks2[S_ * ALD];
  __shared__ float z[DH_], wt[S_], wi[S_], qt[DH_], qi[DH_], at[S_], ai[S_];
  int t = threadIdx.x;
  int b = blockIdx.x >> 2, h = blockIdx.x & 3;
  size_t base = (size_t)b * S_ * TD_;
  int qoff = h * DH_, koff = 768 + h * DH_, voff = 1536 + h * DH_;

  for (int idx = t; idx < S_ * 48; idx += 256) {
    int s = idx / 48, c = (idx % 48) * 4;
    *(ushort4*)(&qs[s * ALD + c])  = *(const ushort4*)(&qkv[base + (size_t)s * TD_ + qoff + c]);
    *(ushort4*)(&ks2[s * ALD + c]) = *(const ushort4*)(&qkv[base + (size_t)s * TD_ + koff + c]);
  }
  __syncthreads();
  if (t < DH_) {
    float a = 0;
    for (int s = 0; s < S_; ++s) a += bf2f(ks2[s * ALD + t]);
    z[t] = a;
  }
  __syncthreads();
  if (t < S_) {
    float a = 0;
    for (int d = 0; d < DH_; ++d) a += bf2f(qs[t * ALD + d]) * z[d];
    float den = a + 1e-6f;
    wt[t] = (t < TEXT_) ? 1.0f / (35.0f * den) : 0.0f;
    wi[t] = (t >= TEXT_) ? 1.0f / (36.0f * den) : 0.0f;
  }
  __syncthreads();
  if (t < DH_) {
    float aT = 0, aI = 0;
    for (int s = 0; s < S_; ++s) {
      float qv = bf2f(qs[s * ALD + t]);
      aT += qv * wt[s]; aI += qv * wi[s];
    }
    qt[t] = aT; qi[t] = aI;
  }
  __syncthreads();
  if (t < S_) {
    float aT = 0, aI = 0;
    for (int d = 0; d < DH_; ++d) {
      float kv = bf2f(ks2[t * ALD + d]);
      aT += kv * qt[d]; aI += kv * qi[d];
    }
    at[t] = aT; ai[t] = aI;
  }
  __syncthreads();
  if (t < DH_) {
    float aT = 0, aI = 0;
    for (int s = 0; s < S_; ++s) {
      float vv = bf2f(qkv[base + (size_t)s * TD_ + voff + t]);
      aT += at[s] * vv; aI += ai[s] * vv;
    }
    mt[(size_t)b * D_ + qoff + t] = aT;
    mi[(size_t)b * D_ + qoff + t] = aI;
  }
}

// ---------------------------------------------------------------------------
// Final head: f = m @ w_out^T + b_out ; r = tanh(f) ; cosine similarity.
// GFIN=4: 512 blocks -> 2 waves/SIMD (GFIN=8's 256 blocks was latency-bound).
#define GFIN 4
__global__ __launch_bounds__(256) void k_final(
    const float* __restrict__ mt, const float* __restrict__ mi,
    const float* __restrict__ wT,   // [768,768] = w_out transposed [d][e]
    const float* __restrict__ bout, // [768]
    float* __restrict__ out)        // [B_]
{
  __shared__ float mts[GFIN][768], mis[GFIN][768];
  __shared__ float red[3][4];
  int t = threadIdx.x, b0 = blockIdx.x * GFIN;
  for (int i = t; i < GFIN * 768; i += 256) {
    int g = i / 768, d = i % 768;
    mts[g][d] = mt[(size_t)(b0 + g) * 768 + d];
    mis[g][d] = mi[(size_t)(b0 + g) * 768 + d];
  }
  __syncthreads();
  float aT[GFIN][3] = {}, aI[GFIN][3] = {};
  for (int d = 0; d < 768; ++d) {
    const float* wrow = wT + (size_t)d * 768 + t;
    float w0 = wrow[0], w1 = wrow[256], w2 = wrow[512];
#pragma unroll
    for (int g = 0; g < GFIN; ++g) {
      float m1 = mts[g][d], m2 = mis[g][d];
      aT[g][0] += m1 * w0; aT[g][1] += m1 * w1; aT[g][2] += m1 * w2;
      aI[g][0] += m2 * w0; aI[g][1] += m2 * w1; aI[g][2] += m2 * w2;
    }
  }
  int lane = t & 63, wid = t >> 6;
  for (int g = 0; g < GFIN; ++g) {
    float st = 0, si = 0, sd = 0;
#pragma unroll
    for (int j = 0; j < 3; ++j) {
      float bo = bout[t + j * 256];
      float rt = tanhf(aT[g][j] + bo);
      float ri = tanhf(aI[g][j] + bo);
      st += rt * rt; si += ri * ri; sd += rt * ri;
    }
#pragma unroll
    for (int off = 32; off >= 1; off >>= 1) {
      st += __shfl_down(st, off);
      si += __shfl_down(si, off);
      sd += __shfl_down(sd, off);
    }
    __syncthreads();
    if (lane == 0) { red[0][wid] = st; red[1][wid] = si; red[2][wid] = sd; }
    __syncthreads();
    if (t == 0) {
      float S1 = red[0][0] + red[0][1] + red[0][2] + red[0][3];
      float S2 = red[1][0] + red[1][1] + red[1][2] + red[1][3];
      float S3 = red[2][0] + red[2][1] + red[2][2] + red[2][3];
      out[b0 + g] = S3 / (fmaxf(sqrtf(S1), 1e-8f) * fmaxf(sqrtf(S2), 1e-8f));
    }
  }
}

// ---------------------------------------------------------------------------
extern "C" void kernel_launch(void* const* d_in, const int* in_sizes, int n_in,
                              void* d_out, int out_size, void* d_ws, size_t ws_size,
                              hipStream_t stream) {
  const float* features = (const float*)d_in[0];
  // d_in[1] = attention_mask (unused by forward)
  const float* w_qkv = (const float*)d_in[2];
  const float* b_qkv = (const float*)d_in[3];
  const float* w_out = (const float*)d_in[4];
  const float* b_out = (const float*)d_in[5];
  float* out = (float*)d_out;

  char* ws = (char*)d_ws;
  size_t off = 0;
  auto alloc = [&](size_t bytes) {
    void* p = ws + off;
    off += (bytes + 255) & ~(size_t)255;
    return p;
  };
  u16* qkv  = (u16*)alloc((size_t)M_ * TD_ * 2);   // 670 MB
  u16* Abf  = (u16*)alloc((size_t)M_ * D_ * 2);    // 223 MB
  u16* Wbf  = (u16*)alloc((size_t)TD_ * D_ * 2);   // 3.5 MB
  float* wT = (float*)alloc((size_t)D_ * D_ * 4);  // 2.4 MB
  float* mt = (float*)alloc((size_t)B_ * D_ * 4);  // 6.3 MB
  float* mi = (float*)alloc((size_t)B_ * D_ * 4);  // 6.3 MB
  (void)ws_size;

  hipLaunchKernelGGL(k_cvt_bf16, dim3((M_ * D_ / 8 + 255) / 256), dim3(256), 0, stream,
                     features, Abf, M_ * D_ / 8);
  hipLaunchKernelGGL(k_cvt_bf16, dim3((TD_ * D_ / 8 + 255) / 256), dim3(256), 0, stream,
                     w_qkv, Wbf, TD_ * D_ / 8);
  hipLaunchKernelGGL(k_transpose768, dim3(2304), dim3(256), 0, stream, w_out, wT);

  hipLaunchKernelGGL(k_gemm_qkv, dim3(9 * 1136), dim3(512), 0, stream,
                     Abf, Wbf, b_qkv, qkv);
  hipLaunchKernelGGL(k_attn, dim3(B_ * H_), dim3(256), 0, stream, qkv, mt, mi);
  hipLaunchKernelGGL(k_final, dim3(B_ / GFIN), dim3(256), 0, stream, mt, mi, wT, b_out, out);
}

// Round 9
// 1103.026 us; speedup vs baseline: 1.0393x; 1.0393x over previous
//
#include <hip/hip_runtime.h>
#include <hip/hip_bf16.h>

#define B_ 2048
#define S_ 71
#define D_ 768
#define H_ 4
#define DH_ 192
#define TD_ 2304            // 3*D
#define M_ (B_ * S_)        // 145408 = 1136*128
#define TEXT_ 35
#define NKT 12              // 768 / 64 K-tiles

typedef unsigned short u16;
typedef unsigned int u32;
typedef __attribute__((ext_vector_type(4))) float f32x4;
typedef __attribute__((ext_vector_type(8))) short bf16x8;

__device__ __forceinline__ u16 f2bf(float f) {
  u32 u = __float_as_uint(f);
  u32 r = (u + 0x7FFFu + ((u >> 16) & 1u)) >> 16;  // RNE
  return (u16)r;
}
__device__ __forceinline__ float bf2f(u16 x) {
  return __uint_as_float(((u32)x) << 16);
}

typedef __attribute__((address_space(1))) const unsigned int GASU;
typedef __attribute__((address_space(3))) unsigned int LASU;
__device__ __forceinline__ void gload16(const void* g, void* l) {
  __builtin_amdgcn_global_load_lds((GASU*)g, (LASU*)l, 16, 0, 0);
}

#define PHASE_BAR() do { __builtin_amdgcn_s_barrier(); asm volatile("" ::: "memory"); } while (0)

// ---------------------------------------------------------------------------
// fp32 -> bf16 elementwise, 8 elems/thread, exact grid
__global__ __launch_bounds__(256) void k_cvt_bf16(const float* __restrict__ in,
                                                  u16* __restrict__ out, int n8) {
  int idx = blockIdx.x * 256 + threadIdx.x;
  if (idx >= n8) return;
  const float4* p = (const float4*)(in + (size_t)idx * 8);
  float4 a = p[0], b = p[1];
  uint4 o;
  o.x = (u32)f2bf(a.x) | ((u32)f2bf(a.y) << 16);
  o.y = (u32)f2bf(a.z) | ((u32)f2bf(a.w) << 16);
  o.z = (u32)f2bf(b.x) | ((u32)f2bf(b.y) << 16);
  o.w = (u32)f2bf(b.z) | ((u32)f2bf(b.w) << 16);
  *(uint4*)(out + (size_t)idx * 8) = o;
}

// ---------------------------------------------------------------------------
// w_out [e][d] -> w_outT [d][e]  (768x768 fp32, tiny)
__global__ void k_transpose768(const float* __restrict__ in, float* __restrict__ out) {
  int idx = blockIdx.x * 256 + threadIdx.x;
  int e = idx / 768, d = idx % 768;
  out[(size_t)d * 768 + e] = in[idx];
}

// ---------------------------------------------------------------------------
// GEMM: C[M,2304] = A[M,768](bf16) * Bw[2304,768](bf16 n-major), bias + phi.
// Pipe-balanced build: 128x256 tile, BK=64 (128B rows + chunk^(row&7) XOR ->
// 0 bank conflicts), 8 waves of 64x64 (acc=64 VGPR), A double-buffered
// (2x16KB) + B single-buffered (32KB) = 64KB LDS, launch_bounds(512,4) ->
// 2 blocks/CU. Per iter: read B frags -> lgkm0 -> bar (B free) -> stage
// B(T+1) + A(T+1 -> alt buf) -> A reads + MFMA (A dbuf: no WAR) -> vmcnt(0)
// -> bar. Cross-block TLP hides the drain tails.
__global__ __launch_bounds__(512, 4) void k_gemm_qkv(
    const u16* __restrict__ Abf,  // [M_,768] bf16
    const u16* __restrict__ Bw,   // [2304,768] bf16 (n-major)
    const float* __restrict__ bias, // [2304]
    u16* __restrict__ C)            // [M_,2304] bf16, phi on cols<1536
{
  // u16 units: A0 [0,8192), A1 [8192,16384), B [16384,32768)
  __shared__ u16 sm[32768];   // 64 KiB
  int t = threadIdx.x;
  int lane = t & 63, wid = t >> 6;
  int wr = wid >> 2, wc = wid & 3;     // 2 x 4 wave grid, wave tile 64x64
  int lr = lane & 15;
  int g4 = lane >> 4;

  // XCD-bijective swizzle: nwg = 10224 = 8*1278; bn inner -> A-panel L2 reuse
  int swz = (blockIdx.x & 7) * 1278 + (blockIdx.x >> 3);
  int bm = swz / 9, bn = swz % 9;
  const size_t arow0 = (size_t)bm * 128;
  const int bcol0 = bn * 256;

  // staging: A 1024 chunks (2/thread), B 2048 chunks (4/thread).
  // chunk c: row=c>>3, LDS dst = c*8 (linear, wave-uniform); source k-granule
  // pre-swizzled: (c&7)^(row&7).
  const u16* srcA[2];
  int dA[2];
#pragma unroll
  for (int j = 0; j < 2; ++j) {
    int c = j * 512 + t;
    srcA[j] = Abf + (arow0 + (c >> 3)) * 768 + ((c & 7) ^ ((c >> 3) & 7)) * 8;
    dA[j] = c * 8;
  }
  const u16* srcB[4];
  int dB[4];
#pragma unroll
  for (int j = 0; j < 4; ++j) {
    int c = j * 512 + t;
    srcB[j] = Bw + (size_t)(bcol0 + (c >> 3)) * 768 + ((c & 7) ^ ((c >> 3) & 7)) * 8;
    dB[j] = 16384 + c * 8;
  }

#define STAGE_A(abuf, ktu) do { \
  gload16(srcA[0] + (ktu), &sm[(abuf) + dA[0]]); \
  gload16(srcA[1] + (ktu), &sm[(abuf) + dA[1]]); \
} while (0)
#define STAGE_B(ktu) do { \
  gload16(srcB[0] + (ktu), &sm[dB[0]]); \
  gload16(srcB[1] + (ktu), &sm[dB[1]]); \
  gload16(srcB[2] + (ktu), &sm[dB[2]]); \
  gload16(srcB[3] + (ktu), &sm[dB[3]]); \
} while (0)

  // fragment addresses: row&7 == lr&7 (wave/mi offsets are multiples of 8/16)
  int gx0 = g4 ^ (lr & 7);             // kk=0 granule; kk=1 -> gx0^4
  int aro = (wr * 64 + lr) * 64;       // + mi*1024 + gx*8  (u16)
  int bro = 16384 + (wc * 64 + lr) * 64;

  f32x4 acc[4][4] = {};

  // prologue: stage tile 0
  STAGE_A(0, 0); STAGE_B(0);
  asm volatile("s_waitcnt vmcnt(0)" ::: "memory");
  PHASE_BAR();

  int curA = 0;
  for (int T = 0; T < NKT; ++T) {
    int nxtA = 8192 - curA;
    bool pf = (T < NKT - 1);
    int ktu = (T + 1) * 64;
    // read all B fragments (single-buffered B must be consumed before restage)
    bf16x8 bfr[4][2];
#pragma unroll
    for (int ni = 0; ni < 4; ++ni) {
      bfr[ni][0] = *(const bf16x8*)(&sm[bro + ni * 1024 + gx0 * 8]);
      bfr[ni][1] = *(const bf16x8*)(&sm[bro + ni * 1024 + (gx0 ^ 4) * 8]);
    }
    asm volatile("s_waitcnt lgkmcnt(0)" ::: "memory");
    __builtin_amdgcn_sched_barrier(0);
    PHASE_BAR();                         // every wave's B reads done
    if (pf) { STAGE_B(ktu); STAGE_A(nxtA, ktu); }
    // A reads (from dbuf, no WAR) + MFMA
    __builtin_amdgcn_s_setprio(1);
#pragma unroll
    for (int kk = 0; kk < 2; ++kk) {
      int gx = gx0 ^ (kk * 4);
      bf16x8 afr[4];
#pragma unroll
      for (int mi = 0; mi < 4; ++mi)
        afr[mi] = *(const bf16x8*)(&sm[curA + aro + mi * 1024 + gx * 8]);
#pragma unroll
      for (int mi = 0; mi < 4; ++mi)
#pragma unroll
        for (int ni = 0; ni < 4; ++ni)
          acc[mi][ni] = __builtin_amdgcn_mfma_f32_16x16x32_bf16(afr[mi], bfr[ni][kk], acc[mi][ni], 0, 0, 0);
    }
    __builtin_amdgcn_s_setprio(0);
    if (pf) {
      asm volatile("s_waitcnt vmcnt(0)" ::: "memory");   // tile T+1 landed
      PHASE_BAR();
    }
    curA = nxtA;
  }

  // epilogue: bias + phi, bf16 stores
#pragma unroll
  for (int mi = 0; mi < 4; ++mi) {
#pragma unroll
    for (int ni = 0; ni < 4; ++ni) {
      int col = bcol0 + wc * 64 + ni * 16 + lr;
      float bb = bias[col];
#pragma unroll
      for (int i = 0; i < 4; ++i) {
        size_t row = arow0 + wr * 64 + mi * 16 + g4 * 4 + i;
        float v = acc[mi][ni][i] + bb;
        if (col < 1536) v = (v > 0.0f) ? (v + 1.0f) : __expf(v);
        C[row * TD_ + col] = f2bf(v);
      }
    }
  }
#undef STAGE_A
#undef STAGE_B
}

// ---------------------------------------------------------------------------
// Attention core, one block per (b,h). Never materializes kv[192][192].
#define ALD 196  // LDS stride for 192-wide bf16 rows

__global__ __launch_bounds__(256) void k_attn(
    const u16* __restrict__ qkv,  // [M_,2304] bf16
    float* __restrict__ mt, float* __restrict__ mi)  // [B_,768] fp32
{
  __shared__ u16 qs[S_ * ALD];
  __shared__ u16 ks2[S_ * ALD];
  __shared__ float z[DH_], wt[S_], wi[S_], qt[DH_], qi[DH_], at[S_], ai[S_];
  int t = threadIdx.x;
  int b = blockIdx.x >> 2, h = blockIdx.x & 3;
  size_t base = (size_t)b * S_ * TD_;
  int qoff = h * DH_, koff = 768 + h * DH_, voff = 1536 + h * DH_;

  for (int idx = t; idx < S_ * 48; idx += 256) {
    int s = idx / 48, c = (idx % 48) * 4;
    *(ushort4*)(&qs[s * ALD + c])  = *(const ushort4*)(&qkv[base + (size_t)s * TD_ + qoff + c]);
    *(ushort4*)(&ks2[s * ALD + c]) = *(const ushort4*)(&qkv[base + (size_t)s * TD_ + koff + c]);
  }
  __syncthreads();
  if (t < DH_) {
    float a = 0;
    for (int s = 0; s < S_; ++s) a += bf2f(ks2[s * ALD + t]);
    z[t] = a;
  }
  __syncthreads();
  if (t < S_) {
    float a = 0;
    for (int d = 0; d < DH_; ++d) a += bf2f(qs[t * ALD + d]) * z[d];
    float den = a + 1e-6f;
    wt[t] = (t < TEXT_) ? 1.0f / (35.0f * den) : 0.0f;
    wi[t] = (t >= TEXT_) ? 1.0f / (36.0f * den) : 0.0f;
  }
  __syncthreads();
  if (t < DH_) {
    float aT = 0, aI = 0;
    for (int s = 0; s < S_; ++s) {
      float qv = bf2f(qs[s * ALD + t]);
      aT += qv * wt[s]; aI += qv * wi[s];
    }
    qt[t] = aT; qi[t] = aI;
  }
  __syncthreads();
  if (t < S_) {
    float aT = 0, aI = 0;
    for (int d = 0; d < DH_; ++d) {
      float kv = bf2f(ks2[t * ALD + d]);
      aT += kv * qt[d]; aI += kv * qi[d];
    }
    at[t] = aT; ai[t] = aI;
  }
  __syncthreads();
  if (t < DH_) {
    float aT = 0, aI = 0;
    for (int s = 0; s < S_; ++s) {
      float vv = bf2f(qkv[base + (size_t)s * TD_ + voff + t]);
      aT += at[s] * vv; aI += ai[s] * vv;
    }
    mt[(size_t)b * D_ + qoff + t] = aT;
    mi[(size_t)b * D_ + qoff + t] = aI;
  }
}

// ---------------------------------------------------------------------------
// Final head: f = m @ w_out^T + b_out ; r = tanh(f) ; cosine similarity.
#define GFIN 4
__global__ __launch_bounds__(256) void k_final(
    const float* __restrict__ mt, const float* __restrict__ mi,
    const float* __restrict__ wT,   // [768,768] = w_out transposed [d][e]
    const float* __restrict__ bout, // [768]
    float* __restrict__ out)        // [B_]
{
  __shared__ float mts[GFIN][768], mis[GFIN][768];
  __shared__ float red[3][4];
  int t = threadIdx.x, b0 = blockIdx.x * GFIN;
  for (int i = t; i < GFIN * 768; i += 256) {
    int g = i / 768, d = i % 768;
    mts[g][d] = mt[(size_t)(b0 + g) * 768 + d];
    mis[g][d] = mi[(size_t)(b0 + g) * 768 + d];
  }
  __syncthreads();
  float aT[GFIN][3] = {}, aI[GFIN][3] = {};
  for (int d = 0; d < 768; ++d) {
    const float* wrow = wT + (size_t)d * 768 + t;
    float w0 = wrow[0], w1 = wrow[256], w2 = wrow[512];
#pragma unroll
    for (int g = 0; g < GFIN; ++g) {
      float m1 = mts[g][d], m2 = mis[g][d];
      aT[g][0] += m1 * w0; aT[g][1] += m1 * w1; aT[g][2] += m1 * w2;
      aI[g][0] += m2 * w0; aI[g][1] += m2 * w1; aI[g][2] += m2 * w2;
    }
  }
  int lane = t & 63, wid = t >> 6;
  for (int g = 0; g < GFIN; ++g) {
    float st = 0, si = 0, sd = 0;
#pragma unroll
    for (int j = 0; j < 3; ++j) {
      float bo = bout[t + j * 256];
      float rt = tanhf(aT[g][j] + bo);
      float ri = tanhf(aI[g][j] + bo);
      st += rt * rt; si += ri * ri; sd += rt * ri;
    }
#pragma unroll
    for (int off = 32; off >= 1; off >>= 1) {
      st += __shfl_down(st, off);
      si += __shfl_down(si, off);
      sd += __shfl_down(sd, off);
    }
    __syncthreads();
    if (lane == 0) { red[0][wid] = st; red[1][wid] = si; red[2][wid] = sd; }
    __syncthreads();
    if (t == 0) {
      float S1 = red[0][0] + red[0][1] + red[0][2] + red[0][3];
      float S2 = red[1][0] + red[1][1] + red[1][2] + red[1][3];
      float S3 = red[2][0] + red[2][1] + red[2][2] + red[2][3];
      out[b0 + g] = S3 / (fmaxf(sqrtf(S1), 1e-8f) * fmaxf(sqrtf(S2), 1e-8f));
    }
  }
}

// ---------------------------------------------------------------------------
extern "C" void kernel_launch(void* const* d_in, const int* in_sizes, int n_in,
                              void* d_out, int out_size, void* d_ws, size_t ws_size,
                              hipStream_t stream) {
  const float* features = (const float*)d_in[0];
  // d_in[1] = attention_mask (unused by forward)
  const float* w_qkv = (const float*)d_in[2];
  const float* b_qkv = (const float*)d_in[3];
  const float* w_out = (const float*)d_in[4];
  const float* b_out = (const float*)d_in[5];
  float* out = (float*)d_out;

  char* ws = (char*)d_ws;
  size_t off = 0;
  auto alloc = [&](size_t bytes) {
    void* p = ws + off;
    off += (bytes + 255) & ~(size_t)255;
    return p;
  };
  u16* qkv  = (u16*)alloc((size_t)M_ * TD_ * 2);   // 670 MB
  u16* Abf  = (u16*)alloc((size_t)M_ * D_ * 2);    // 223 MB
  u16* Wbf  = (u16*)alloc((size_t)TD_ * D_ * 2);   // 3.5 MB
  float* wT = (float*)alloc((size_t)D_ * D_ * 4);  // 2.4 MB
  float* mt = (float*)alloc((size_t)B_ * D_ * 4);  // 6.3 MB
  float* mi = (float*)alloc((size_t)B_ * D_ * 4);  // 6.3 MB
  (void)ws_size;

  hipLaunchKernelGGL(k_cvt_bf16, dim3((M_ * D_ / 8 + 255) / 256), dim3(256), 0, stream,
                     features, Abf, M_ * D_ / 8);
  hipLaunchKernelGGL(k_cvt_bf16, dim3((TD_ * D_ / 8 + 255) / 256), dim3(256), 0, stream,
                     w_qkv, Wbf, TD_ * D_ / 8);
  hipLaunchKernelGGL(k_transpose768, dim3(2304), dim3(256), 0, stream, w_out, wT);

  hipLaunchKernelGGL(k_gemm_qkv, dim3(9 * 1136), dim3(512), 0, stream,
                     Abf, Wbf, b_qkv, qkv);
  hipLaunchKernelGGL(k_attn, dim3(B_ * H_), dim3(256), 0, stream, qkv, mt, mi);
  hipLaunchKernelGGL(k_final, dim3(B_ / GFIN), dim3(256), 0, stream, mt, mi, wT, b_out, out);
}

// Round 10
// 1087.330 us; speedup vs baseline: 1.0543x; 1.0144x over previous
//
#include <hip/hip_runtime.h>
#include <hip/hip_bf16.h>

#define B_ 2048
#define S_ 71
#define D_ 768
#define H_ 4
#define DH_ 192
#define TD_ 2304            // 3*D
#define M_ (B_ * S_)        // 145408 = 1136*128
#define TEXT_ 35
#define NKT 12              // 768 / 64 K-tiles

typedef unsigned short u16;
typedef unsigned int u32;
typedef __attribute__((ext_vector_type(4))) float f32x4;
typedef __attribute__((ext_vector_type(8))) short bf16x8;

__device__ __forceinline__ u16 f2bf(float f) {
  u32 u = __float_as_uint(f);
  u32 r = (u + 0x7FFFu + ((u >> 16) & 1u)) >> 16;  // RNE
  return (u16)r;
}
__device__ __forceinline__ float bf2f(u16 x) {
  return __uint_as_float(((u32)x) << 16);
}

typedef __attribute__((address_space(1))) const unsigned int GASU;
typedef __attribute__((address_space(3))) unsigned int LASU;
__device__ __forceinline__ void gload16(const void* g, void* l) {
  __builtin_amdgcn_global_load_lds((GASU*)g, (LASU*)l, 16, 0, 0);
}

#define PHASE_BAR() do { __builtin_amdgcn_s_barrier(); asm volatile("" ::: "memory"); } while (0)
#define LGKM0() do { asm volatile("s_waitcnt lgkmcnt(0)" ::: "memory"); __builtin_amdgcn_sched_barrier(0); } while (0)

// ---------------------------------------------------------------------------
// fp32 -> bf16 elementwise, 8 elems/thread, exact grid (used for w_qkv only)
__global__ __launch_bounds__(256) void k_cvt_bf16(const float* __restrict__ in,
                                                  u16* __restrict__ out, int n8) {
  int idx = blockIdx.x * 256 + threadIdx.x;
  if (idx >= n8) return;
  const float4* p = (const float4*)(in + (size_t)idx * 8);
  float4 a = p[0], b = p[1];
  uint4 o;
  o.x = (u32)f2bf(a.x) | ((u32)f2bf(a.y) << 16);
  o.y = (u32)f2bf(a.z) | ((u32)f2bf(a.w) << 16);
  o.z = (u32)f2bf(b.x) | ((u32)f2bf(b.y) << 16);
  o.w = (u32)f2bf(b.z) | ((u32)f2bf(b.w) << 16);
  *(uint4*)(out + (size_t)idx * 8) = o;
}

// ---------------------------------------------------------------------------
// w_out [e][d] -> w_outT [d][e]  (768x768 fp32, tiny)
__global__ void k_transpose768(const float* __restrict__ in, float* __restrict__ out) {
  int idx = blockIdx.x * 256 + threadIdx.x;
  int e = idx / 768, d = idx % 768;
  out[(size_t)d * 768 + e] = in[idx];
}

// ---------------------------------------------------------------------------
// GEMM: C[M,2304] = A[M,768](fp32, converted in-kernel) * Bw[2304,768](bf16),
// bias + phi epilogue. 128x256 tile, BK=64, 8 waves 64x64, A dbuf (2x16KB) +
// B single (32KB) = 64KB LDS, launch_bounds(512,4) -> 2 blocks/CU.
// A is REG-STAGED (fp32 global -> f2bf -> ds_write): kills the separate
// 670MB cvt pass. Reg budget: B-frag reads split per kk-half (16 live regs
// not 32) to make room for the 16 staged fp32. Per iter:
//   [read bfr0+afr0; MFMA kk0; read bfr1; lgkm0; BAR (B free);
//    STAGE_B(T+1) + load A(T+1) fp32; read afr1; MFMA kk1;
//    vmcnt(0); cvt+ds_write A(T+1)->alt buf; lgkm0; BAR]
__global__ __launch_bounds__(512, 4) void k_gemm_qkv(
    const float* __restrict__ Afp,  // [M_,768] fp32 (features)
    const u16* __restrict__ Bw,     // [2304,768] bf16 (n-major)
    const float* __restrict__ bias, // [2304]
    u16* __restrict__ C)            // [M_,2304] bf16, phi on cols<1536
{
  // u16 units: A0 [0,8192), A1 [8192,16384), B [16384,32768)
  __shared__ u16 sm[32768];   // 64 KiB
  int t = threadIdx.x;
  int lane = t & 63, wid = t >> 6;
  int wr = wid >> 2, wc = wid & 3;     // 2 x 4 wave grid, wave tile 64x64
  int lr = lane & 15;
  int g4 = lane >> 4;

  // XCD-bijective swizzle: nwg = 10224 = 8*1278; bn inner -> A-panel L2 reuse
  int swz = (blockIdx.x & 7) * 1278 + (blockIdx.x >> 3);
  int bm = swz / 9, bn = swz % 9;
  const size_t arow0 = (size_t)bm * 128;
  const int bcol0 = bn * 256;

  // A: 1024 granule-chunks (8 elems), 2/thread. chunk c: row=c>>3, source
  // granule pre-swizzled (c&7)^(row&7); LDS dst linear c*8 (u16).
  const float* srcAf[2];
  int dA[2];
#pragma unroll
  for (int j = 0; j < 2; ++j) {
    int c = j * 512 + t;
    srcAf[j] = Afp + (arow0 + (c >> 3)) * 768 + ((c & 7) ^ ((c >> 3) & 7)) * 8;
    dA[j] = c * 8;
  }
  // B: gload_lds, 2048 chunks, 4/thread (same pre-swizzled source)
  const u16* srcB[4];
  int dB[4];
#pragma unroll
  for (int j = 0; j < 4; ++j) {
    int c = j * 512 + t;
    srcB[j] = Bw + (size_t)(bcol0 + (c >> 3)) * 768 + ((c & 7) ^ ((c >> 3) & 7)) * 8;
    dB[j] = 16384 + c * 8;
  }

#define STAGE_B(ktu) do { \
  gload16(srcB[0] + (ktu), &sm[dB[0]]); \
  gload16(srcB[1] + (ktu), &sm[dB[1]]); \
  gload16(srcB[2] + (ktu), &sm[dB[2]]); \
  gload16(srcB[3] + (ktu), &sm[dB[3]]); \
} while (0)
#define LOADA(ktu) do { \
  fa0 = *(const float4*)(srcAf[0] + (ktu)); \
  fa1 = *(const float4*)(srcAf[0] + (ktu) + 4); \
  fa2 = *(const float4*)(srcAf[1] + (ktu)); \
  fa3 = *(const float4*)(srcAf[1] + (ktu) + 4); \
} while (0)
#define PK2(lo, hi) ((u32)f2bf(lo) | ((u32)f2bf(hi) << 16))
#define WRITEA(abuf) do { \
  uint4 o0; \
  o0.x = PK2(fa0.x, fa0.y); o0.y = PK2(fa0.z, fa0.w); \
  o0.z = PK2(fa1.x, fa1.y); o0.w = PK2(fa1.z, fa1.w); \
  *(uint4*)(&sm[(abuf) + dA[0]]) = o0; \
  uint4 o1; \
  o1.x = PK2(fa2.x, fa2.y); o1.y = PK2(fa2.z, fa2.w); \
  o1.z = PK2(fa3.x, fa3.y); o1.w = PK2(fa3.z, fa3.w); \
  *(uint4*)(&sm[(abuf) + dA[1]]) = o1; \
} while (0)

  // fragment addresses (swizzled read side, unchanged from round 9)
  int gx0 = g4 ^ (lr & 7);             // kk=0 granule; kk=1 -> gx0^4
  int aro = (wr * 64 + lr) * 64;       // + mi*1024 + gx*8  (u16)
  int bro = 16384 + (wc * 64 + lr) * 64;

  f32x4 acc[4][4] = {};
  float4 fa0, fa1, fa2, fa3;

  // prologue: stage tile 0 (A via regs, B via gload_lds)
  LOADA(0);
  STAGE_B(0);
  asm volatile("s_waitcnt vmcnt(0)" ::: "memory");
  WRITEA(0);
  asm volatile("s_waitcnt lgkmcnt(0)" ::: "memory");
  PHASE_BAR();

  int curA = 0;
  for (int T = 0; T < NKT; ++T) {
    int nxtA = 8192 - curA;
    bool pf = (T < NKT - 1);
    int ktu = (T + 1) * 64;
    // ---- kk0: B frags + A frags, MFMA ----
    bf16x8 b0[4], a0[4];
#pragma unroll
    for (int ni = 0; ni < 4; ++ni) b0[ni] = *(const bf16x8*)(&sm[bro + ni * 1024 + gx0 * 8]);
#pragma unroll
    for (int mi = 0; mi < 4; ++mi) a0[mi] = *(const bf16x8*)(&sm[curA + aro + mi * 1024 + gx0 * 8]);
    __builtin_amdgcn_s_setprio(1);
#pragma unroll
    for (int mi = 0; mi < 4; ++mi)
#pragma unroll
      for (int ni = 0; ni < 4; ++ni)
        acc[mi][ni] = __builtin_amdgcn_mfma_f32_16x16x32_bf16(a0[mi], b0[ni], acc[mi][ni], 0, 0, 0);
    __builtin_amdgcn_s_setprio(0);
    // ---- kk1 B reads must finish before B restage ----
    int gx1 = gx0 ^ 4;
    bf16x8 b1[4];
#pragma unroll
    for (int ni = 0; ni < 4; ++ni) b1[ni] = *(const bf16x8*)(&sm[bro + ni * 1024 + gx1 * 8]);
    LGKM0();
    PHASE_BAR();                       // every wave's B reads done -> B free
    if (pf) { STAGE_B(ktu); LOADA(ktu); }
    // ---- kk1: A frags + MFMA (A dbuf: no WAR with tail write) ----
    bf16x8 a1[4];
#pragma unroll
    for (int mi = 0; mi < 4; ++mi) a1[mi] = *(const bf16x8*)(&sm[curA + aro + mi * 1024 + gx1 * 8]);
    __builtin_amdgcn_s_setprio(1);
#pragma unroll
    for (int mi = 0; mi < 4; ++mi)
#pragma unroll
      for (int ni = 0; ni < 4; ++ni)
        acc[mi][ni] = __builtin_amdgcn_mfma_f32_16x16x32_bf16(a1[mi], b1[ni], acc[mi][ni], 0, 0, 0);
    __builtin_amdgcn_s_setprio(0);
    if (pf) {
      asm volatile("s_waitcnt vmcnt(0)" ::: "memory");   // B(T+1) landed, A regs ready
      WRITEA(nxtA);
      asm volatile("s_waitcnt lgkmcnt(0)" ::: "memory"); // ds_writes committed
      PHASE_BAR();
    }
    curA = nxtA;
  }

  // epilogue: bias + phi, bf16 stores
#pragma unroll
  for (int mi = 0; mi < 4; ++mi) {
#pragma unroll
    for (int ni = 0; ni < 4; ++ni) {
      int col = bcol0 + wc * 64 + ni * 16 + lr;
      float bb = bias[col];
#pragma unroll
      for (int i = 0; i < 4; ++i) {
        size_t row = arow0 + wr * 64 + mi * 16 + g4 * 4 + i;
        float v = acc[mi][ni][i] + bb;
        if (col < 1536) v = (v > 0.0f) ? (v + 1.0f) : __expf(v);
        C[row * TD_ + col] = f2bf(v);
      }
    }
  }
#undef STAGE_B
#undef LOADA
#undef WRITEA
}

// ---------------------------------------------------------------------------
// Attention core, one block per (b,h). Never materializes kv[192][192].
#define ALD 196  // LDS stride for 192-wide bf16 rows

__global__ __launch_bounds__(256) void k_attn(
    const u16* __restrict__ qkv,  // [M_,2304] bf16
    float* __restrict__ mt, float* __restrict__ mi)  // [B_,768] fp32
{
  __shared__ u16 qs[S_ * ALD];
  __shared__ u16 ks2[S_ * ALD];
  __shared__ float z[DH_], wt[S_], wi[S_], qt[DH_], qi[DH_], at[S_], ai[S_];
  int t = threadIdx.x;
  int b = blockIdx.x >> 2, h = blockIdx.x & 3;
  size_t base = (size_t)b * S_ * TD_;
  int qoff = h * DH_, koff = 768 + h * DH_, voff = 1536 + h * DH_;

  for (int idx = t; idx < S_ * 48; idx += 256) {
    int s = idx / 48, c = (idx % 48) * 4;
    *(ushort4*)(&qs[s * ALD + c])  = *(const ushort4*)(&qkv[base + (size_t)s * TD_ + qoff + c]);
    *(ushort4*)(&ks2[s * ALD + c]) = *(const ushort4*)(&qkv[base + (size_t)s * TD_ + koff + c]);
  }
  __syncthreads();
  if (t < DH_) {
    float a = 0;
    for (int s = 0; s < S_; ++s) a += bf2f(ks2[s * ALD + t]);
    z[t] = a;
  }
  __syncthreads();
  if (t < S_) {
    float a = 0;
    for (int d = 0; d < DH_; ++d) a += bf2f(qs[t * ALD + d]) * z[d];
    float den = a + 1e-6f;
    wt[t] = (t < TEXT_) ? 1.0f / (35.0f * den) : 0.0f;
    wi[t] = (t >= TEXT_) ? 1.0f / (36.0f * den) : 0.0f;
  }
  __syncthreads();
  if (t < DH_) {
    float aT = 0, aI = 0;
    for (int s = 0; s < S_; ++s) {
      float qv = bf2f(qs[s * ALD + t]);
      aT += qv * wt[s]; aI += qv * wi[s];
    }
    qt[t] = aT; qi[t] = aI;
  }
  __syncthreads();
  if (t < S_) {
    float aT = 0, aI = 0;
    for (int d = 0; d < DH_; ++d) {
      float kv = bf2f(ks2[t * ALD + d]);
      aT += kv * qt[d]; aI += kv * qi[d];
    }
    at[t] = aT; ai[t] = aI;
  }
  __syncthreads();
  if (t < DH_) {
    float aT = 0, aI = 0;
    for (int s = 0; s < S_; ++s) {
      float vv = bf2f(qkv[base + (size_t)s * TD_ + voff + t]);
      aT += at[s] * vv; aI += ai[s] * vv;
    }
    mt[(size_t)b * D_ + qoff + t] = aT;
    mi[(size_t)b * D_ + qoff + t] = aI;
  }
}

// ---------------------------------------------------------------------------
// Final head: f = m @ w_out^T + b_out ; r = tanh(f) ; cosine similarity.
#define GFIN 4
__global__ __launch_bounds__(256) void k_final(
    const float* __restrict__ mt, const float* __restrict__ mi,
    const float* __restrict__ wT,   // [768,768] = w_out transposed [d][e]
    const float* __restrict__ bout, // [768]
    float* __restrict__ out)        // [B_]
{
  __shared__ float mts[GFIN][768], mis[GFIN][768];
  __shared__ float red[3][4];
  int t = threadIdx.x, b0 = blockIdx.x * GFIN;
  for (int i = t; i < GFIN * 768; i += 256) {
    int g = i / 768, d = i % 768;
    mts[g][d] = mt[(size_t)(b0 + g) * 768 + d];
    mis[g][d] = mi[(size_t)(b0 + g) * 768 + d];
  }
  __syncthreads();
  float aT[GFIN][3] = {}, aI[GFIN][3] = {};
  for (int d = 0; d < 768; ++d) {
    const float* wrow = wT + (size_t)d * 768 + t;
    float w0 = wrow[0], w1 = wrow[256], w2 = wrow[512];
#pragma unroll
    for (int g = 0; g < GFIN; ++g) {
      float m1 = mts[g][d], m2 = mis[g][d];
      aT[g][0] += m1 * w0; aT[g][1] += m1 * w1; aT[g][2] += m1 * w2;
      aI[g][0] += m2 * w0; aI[g][1] += m2 * w1; aI[g][2] += m2 * w2;
    }
  }
  int lane = t & 63, wid = t >> 6;
  for (int g = 0; g < GFIN; ++g) {
    float st = 0, si = 0, sd = 0;
#pragma unroll
    for (int j = 0; j < 3; ++j) {
      float bo = bout[t + j * 256];
      float rt = tanhf(aT[g][j] + bo);
      float ri = tanhf(aI[g][j] + bo);
      st += rt * rt; si += ri * ri; sd += rt * ri;
    }
#pragma unroll
    for (int off = 32; off >= 1; off >>= 1) {
      st += __shfl_down(st, off);
      si += __shfl_down(si, off);
      sd += __shfl_down(sd, off);
    }
    __syncthreads();
    if (lane == 0) { red[0][wid] = st; red[1][wid] = si; red[2][wid] = sd; }
    __syncthreads();
    if (t == 0) {
      float S1 = red[0][0] + red[0][1] + red[0][2] + red[0][3];
      float S2 = red[1][0] + red[1][1] + red[1][2] + red[1][3];
      float S3 = red[2][0] + red[2][1] + red[2][2] + red[2][3];
      out[b0 + g] = S3 / (fmaxf(sqrtf(S1), 1e-8f) * fmaxf(sqrtf(S2), 1e-8f));
    }
  }
}

// ---------------------------------------------------------------------------
extern "C" void kernel_launch(void* const* d_in, const int* in_sizes, int n_in,
                              void* d_out, int out_size, void* d_ws, size_t ws_size,
                              hipStream_t stream) {
  const float* features = (const float*)d_in[0];
  // d_in[1] = attention_mask (unused by forward)
  const float* w_qkv = (const float*)d_in[2];
  const float* b_qkv = (const float*)d_in[3];
  const float* w_out = (const float*)d_in[4];
  const float* b_out = (const float*)d_in[5];
  float* out = (float*)d_out;

  char* ws = (char*)d_ws;
  size_t off = 0;
  auto alloc = [&](size_t bytes) {
    void* p = ws + off;
    off += (bytes + 255) & ~(size_t)255;
    return p;
  };
  u16* qkv  = (u16*)alloc((size_t)M_ * TD_ * 2);   // 670 MB
  u16* Wbf  = (u16*)alloc((size_t)TD_ * D_ * 2);   // 3.5 MB
  float* wT = (float*)alloc((size_t)D_ * D_ * 4);  // 2.4 MB
  float* mt = (float*)alloc((size_t)B_ * D_ * 4);  // 6.3 MB
  float* mi = (float*)alloc((size_t)B_ * D_ * 4);  // 6.3 MB
  (void)ws_size;

  hipLaunchKernelGGL(k_cvt_bf16, dim3((TD_ * D_ / 8 + 255) / 256), dim3(256), 0, stream,
                     w_qkv, Wbf, TD_ * D_ / 8);
  hipLaunchKernelGGL(k_transpose768, dim3(2304), dim3(256), 0, stream, w_out, wT);

  hipLaunchKernelGGL(k_gemm_qkv, dim3(9 * 1136), dim3(512), 0, stream,
                     features, Wbf, b_qkv, qkv);
  hipLaunchKernelGGL(k_attn, dim3(B_ * H_), dim3(256), 0, stream, qkv, mt, mi);
  hipLaunchKernelGGL(k_final, dim3(B_ / GFIN), dim3(256), 0, stream, mt, mi, wT, b_out, out);
}